// Round 11
// baseline (126.780 us; speedup 1.0000x reference)
//
#include <hip/hip_runtime.h>

// GraphConv: h = x @ W + b, then out[b,r] = sum_e vals[e]*h[b,cols[e]]
// B=2, V=50000, C=128, F=128, E=800000
// Round 11: inline-cnt slot rows (128B: cnt + 31 payloads -> atomic and
// dependent store hit the SAME line) + overflow list (no silent drops).
// W pre-converted to frag-linear bf16 (wprep) -> gemm has no LDS/barrier.
// Fused scatter||gemm prep, interleaved h, 16-wide spmm.

#define NB 2
#define NV 50000
#define NC 128
#define NF 128
#define NE 800000
#define NROW (NB * NV)       // 100000
#define CAPR 31              // payloads per 128B slot row
#define ROWW 32              // words per slot row
#define OVF_MAX 4096

#define SCAT_BLOCKS ((NE / 4 + 511) / 512)   // 391
#define GEMM_BLOCKS ((NROW + 127) / 128)     // 782

// ---- workspace layout (bytes) ----
#define WS_WF_OFF    0UL
#define WS_WF_BYTES  32768UL                                  // frag-linear bf16 W
#define WS_H_OFF     (WS_WF_OFF + WS_WF_BYTES)
#define WS_H_BYTES   ((size_t)NROW * NF * 2UL)                // 25,600,000
#define WS_SLOT_OFF  (WS_H_OFF + WS_H_BYTES)
#define WS_SLOT_BYTES ((size_t)NV * ROWW * 4UL)               // 6,400,000
#define WS_OVFC_OFF  (WS_SLOT_OFF + WS_SLOT_BYTES)
#define WS_OVFC_BYTES 256UL
#define WS_OVF_OFF   (WS_OVFC_OFF + WS_OVFC_BYTES)
#define WS_OVF_BYTES ((size_t)OVF_MAX * 8UL)
#define WS_NEEDED    (WS_OVF_OFF + WS_OVF_BYTES)              // ~32.1 MB
#define WS_ZERO_BYTES (WS_SLOT_BYTES + WS_OVFC_BYTES + WS_OVF_BYTES)

typedef __attribute__((ext_vector_type(8))) short short8v;  // 8 bf16 bits
typedef __attribute__((ext_vector_type(4))) float f32x4;

// fp32 -> bf16 bits, round-to-nearest-even
__device__ __forceinline__ unsigned short f2b(float f) {
    unsigned int u = __float_as_uint(f);
    u += 0x7fffu + ((u >> 16) & 1u);
    return (unsigned short)(u >> 16);
}

__device__ __forceinline__ unsigned packslot(int col, float val) {
    return ((unsigned)col << 16) | (unsigned)f2b(val);
}

// ---------------- Kernel 0: W -> frag-linear bf16 (once) ----------------
// slot s = (ks*8+nt)*64+lane holds 8 bf16:
//   Wf[s*8+j] = W[(ks*32+((lane>>4)&3)*8+j)*NF + nt*16+(lane&15)]
__global__ __launch_bounds__(256) void wprep_kernel(
    const float* __restrict__ W, unsigned short* __restrict__ Wf) {
    int s = blockIdx.x * 256 + threadIdx.x;
    if (s >= 2048) return;
    int lane = s & 63;
    int nt = (s >> 6) & 7;
    int ks = s >> 9;
    int n = nt * 16 + (lane & 15);
    int kb = ks * 32 + ((lane >> 4) & 3) * 8;
    short8v f;
#pragma unroll
    for (int j = 0; j < 8; ++j)
        f[j] = (short)f2b(W[(kb + j) * NF + n]);
    *(short8v*)(Wf + (size_t)s * 8) = f;
}

__device__ __forceinline__ void scat_one(
    unsigned* __restrict__ slot, int* __restrict__ ovfc,
    uint2* __restrict__ ovf, int r, int c, float v) {
    unsigned* srow = slot + (size_t)r * ROWW;
    int p = atomicAdd((int*)srow, 1);
    if (p < CAPR) {
        srow[1 + p] = packslot(c, v);          // same 128B region as the atomic
    } else {
        int q = atomicAdd(ovfc, 1);
        if (q < OVF_MAX)
            ovf[q] = make_uint2(((unsigned)r << 16) | (unsigned)c,
                                __float_as_uint(v));
    }
}

// ---------------- Kernel 1: fused scatter + MFMA GEMM (no LDS) -------------
// Blocks [0, SCAT_BLOCKS): slot scatter, 1 edge-quad per thread.
// Blocks [SCAT_BLOCKS, +GEMM_BLOCKS): bf16 MFMA gemm; B-frags loaded straight
//   from global frag-linear Wf (1KB coalesced per wave per frag, L1-resident).
//   h interleaved: h[node*256 + batch*128 + c].
__global__ __launch_bounds__(512) void prep_kernel(
    const float* __restrict__ x, const unsigned short* __restrict__ Wf,
    const float* __restrict__ bias, unsigned short* __restrict__ h,
    const int4* __restrict__ rows4, const int4* __restrict__ cols4,
    const float4* __restrict__ vals4, unsigned* __restrict__ slot,
    int* __restrict__ ovfc, uint2* __restrict__ ovf) {
    int tid = threadIdx.x;

    if (blockIdx.x < SCAT_BLOCKS) {
        int t = blockIdx.x * 512 + tid;
        if (t >= NE / 4) return;
        int4 r4 = rows4[t];
        int4 c4 = cols4[t];
        float4 v4 = vals4[t];
        scat_one(slot, ovfc, ovf, r4.x, c4.x, v4.x);
        scat_one(slot, ovfc, ovf, r4.y, c4.y, v4.y);
        scat_one(slot, ovfc, ovf, r4.z, c4.z, v4.z);
        scat_one(slot, ovfc, ovf, r4.w, c4.w, v4.w);
        return;
    }

    // ---------------- GEMM part ----------------
    int gb = blockIdx.x - SCAT_BLOCKS;
    int wid = tid >> 6;
    int lane = tid & 63;
    long long rowbase = (long long)gb * 128 + wid * 16;
    if (rowbase >= NROW) return;

    int arow = (int)rowbase + (lane & 15);
    int khi = lane >> 4;
    f32x4 acc[8];
#pragma unroll
    for (int n = 0; n < 8; ++n) acc[n] = (f32x4){0.f, 0.f, 0.f, 0.f};

#pragma unroll
    for (int ks = 0; ks < 4; ++ks) {
        const float* xp = x + (size_t)arow * NC + ks * 32 + khi * 8;
        float4 xlo = *(const float4*)xp;
        float4 xhi = *(const float4*)(xp + 4);
        short8v af;
        af[0] = (short)f2b(xlo.x); af[1] = (short)f2b(xlo.y);
        af[2] = (short)f2b(xlo.z); af[3] = (short)f2b(xlo.w);
        af[4] = (short)f2b(xhi.x); af[5] = (short)f2b(xhi.y);
        af[6] = (short)f2b(xhi.z); af[7] = (short)f2b(xhi.w);
#pragma unroll
        for (int nt = 0; nt < 8; ++nt) {
            short8v bf = *(const short8v*)(Wf + ((size_t)(ks * 8 + nt) * 64 + lane) * 8);
            acc[nt] = __builtin_amdgcn_mfma_f32_16x16x32_bf16(af, bf, acc[nt], 0, 0, 0);
        }
    }

    int rq = (lane >> 4) * 4;
#pragma unroll
    for (int nt = 0; nt < 8; ++nt) {
        int c = nt * 16 + (lane & 15);
        float bv = bias[c];
#pragma unroll
        for (int reg = 0; reg < 4; ++reg) {
            long long r = rowbase + rq + reg;
            int node = (r >= NV) ? (int)(r - NV) : (int)r;
            int bb = (r >= NV) ? 1 : 0;
            h[(size_t)node * 256 + bb * 128 + c] = f2b(acc[nt][reg] + bv);
        }
    }
}

// ---------------- Kernel 2: slot SpMM, one wave/row, BOTH batches ----------
__global__ __launch_bounds__(256) void spmm_kernel(
    const unsigned* __restrict__ slot, const int* __restrict__ ovfc,
    const uint2* __restrict__ ovf, const unsigned short* __restrict__ h,
    float* __restrict__ out) {
    int r = (blockIdx.x * 256 + threadIdx.x) >> 6;
    int lane = threadIdx.x & 63;
    if (r >= NV) return;
    const unsigned* sp = slot + (size_t)r * ROWW;
    int cnt = (int)sp[0];
    int n = min(cnt, CAPR);
    const unsigned short* hl = h + lane * 2;
    float a0x = 0.f, a0y = 0.f, a1x = 0.f, a1y = 0.f;

    for (int i = 0; i < n; i += 16) {
        unsigned pk[16];
#pragma unroll
        for (int k = 0; k < 16; ++k) {
            int j = i + k;
            pk[k] = (j < n) ? sp[1 + j] : 0u;   // col 0, val 0 (harmless)
        }
        unsigned q0[16], q1[16];
#pragma unroll
        for (int k = 0; k < 16; ++k) {
            size_t base = (size_t)(pk[k] >> 16) * 256;
            q0[k] = *(const unsigned int*)(hl + base);
            q1[k] = *(const unsigned int*)(hl + base + 128);
        }
#pragma unroll
        for (int k = 0; k < 16; ++k) {
            float v = __uint_as_float((pk[k] & 0xffffu) << 16);
            a0x = fmaf(v, __uint_as_float(q0[k] << 16), a0x);
            a0y = fmaf(v, __uint_as_float(q0[k] & 0xffff0000u), a0y);
            a1x = fmaf(v, __uint_as_float(q1[k] << 16), a1x);
            a1y = fmaf(v, __uint_as_float(q1[k] & 0xffff0000u), a1y);
        }
    }

    if (cnt > CAPR) {                         // rare (~10 rows); wave-uniform
        int oc = min(*ovfc, OVF_MAX);
        for (int j = 0; j < oc; ++j) {
            uint2 e = ovf[j];
            if ((e.x >> 16) == (unsigned)r) {
                size_t base = (size_t)(e.x & 0xffffu) * 256;
                float v = __uint_as_float(e.y);
                unsigned w0 = *(const unsigned int*)(hl + base);
                unsigned w1 = *(const unsigned int*)(hl + base + 128);
                a0x = fmaf(v, __uint_as_float(w0 << 16), a0x);
                a0y = fmaf(v, __uint_as_float(w0 & 0xffff0000u), a0y);
                a1x = fmaf(v, __uint_as_float(w1 << 16), a1x);
                a1y = fmaf(v, __uint_as_float(w1 & 0xffff0000u), a1y);
            }
        }
    }

    *(float2*)(out + (size_t)r * NF + lane * 2) = make_float2(a0x, a0y);
    *(float2*)(out + ((size_t)NV + r) * NF + lane * 2) = make_float2(a1x, a1y);
}

// ---------------- Fallback (ws too small): atomic spmm --------------------
__global__ __launch_bounds__(256) void spmm_atomic_kernel(
    const int* __restrict__ rows, const int* __restrict__ cols,
    const float* __restrict__ vals, const unsigned short* __restrict__ h,
    float* __restrict__ out) {
    long long wave = ((long long)blockIdx.x * blockDim.x + threadIdx.x) >> 6;
    int lane = threadIdx.x & 63;
    long long total = (long long)NE * NB;
    if (wave >= total) return;
    int b = (wave >= NE) ? 1 : 0;
    int e = (int)(wave - (long long)b * NE);
    int r = rows[e];
    int c = cols[e];
    float v = vals[e];
    unsigned int hv = *(const unsigned int*)(h + (size_t)c * 256 + b * 128 + lane * 2);
    float h0 = __uint_as_float(hv << 16);
    float h1 = __uint_as_float(hv & 0xffff0000u);
    float* op = out + ((size_t)b * NV + r) * NF + lane * 2;
    atomicAdd(op + 0, v * h0);
    atomicAdd(op + 1, v * h1);
}

// gemm-only for the fallback path (uses frag-linear Wf, interleaved h)
__global__ __launch_bounds__(512) void gemm_only_kernel(
    const float* __restrict__ x, const unsigned short* __restrict__ Wf,
    const float* __restrict__ bias, unsigned short* __restrict__ h) {
    int tid = threadIdx.x;
    int wid = tid >> 6;
    int lane = tid & 63;
    long long rowbase = (long long)blockIdx.x * 128 + wid * 16;
    if (rowbase >= NROW) return;
    int arow = (int)rowbase + (lane & 15);
    int khi = lane >> 4;
    f32x4 acc[8];
#pragma unroll
    for (int n = 0; n < 8; ++n) acc[n] = (f32x4){0.f, 0.f, 0.f, 0.f};
#pragma unroll
    for (int ks = 0; ks < 4; ++ks) {
        const float* xp = x + (size_t)arow * NC + ks * 32 + khi * 8;
        float4 xlo = *(const float4*)xp;
        float4 xhi = *(const float4*)(xp + 4);
        short8v af;
        af[0] = (short)f2b(xlo.x); af[1] = (short)f2b(xlo.y);
        af[2] = (short)f2b(xlo.z); af[3] = (short)f2b(xlo.w);
        af[4] = (short)f2b(xhi.x); af[5] = (short)f2b(xhi.y);
        af[6] = (short)f2b(xhi.z); af[7] = (short)f2b(xhi.w);
#pragma unroll
        for (int nt = 0; nt < 8; ++nt) {
            short8v bf = *(const short8v*)(Wf + ((size_t)(ks * 8 + nt) * 64 + lane) * 8);
            acc[nt] = __builtin_amdgcn_mfma_f32_16x16x32_bf16(af, bf, acc[nt], 0, 0, 0);
        }
    }
    int rq = (lane >> 4) * 4;
#pragma unroll
    for (int nt = 0; nt < 8; ++nt) {
        int c = nt * 16 + (lane & 15);
        float bv = bias[c];
#pragma unroll
        for (int reg = 0; reg < 4; ++reg) {
            long long r = rowbase + rq + reg;
            int node = (r >= NV) ? (int)(r - NV) : (int)r;
            int bb = (r >= NV) ? 1 : 0;
            h[(size_t)node * 256 + bb * 128 + c] = f2b(acc[nt][reg] + bv);
        }
    }
}

extern "C" void kernel_launch(void* const* d_in, const int* in_sizes, int n_in,
                              void* d_out, int out_size, void* d_ws, size_t ws_size,
                              hipStream_t stream) {
    const float* x    = (const float*)d_in[0];
    const int*   rows = (const int*)  d_in[1];
    const int*   cols = (const int*)  d_in[2];
    const float* vals = (const float*)d_in[3];
    const float* W    = (const float*)d_in[4];
    const float* bias = (const float*)d_in[5];
    float* out = (float*)d_out;
    char* ws = (char*)d_ws;

    unsigned short* Wf = (unsigned short*)(ws + WS_WF_OFF);
    unsigned short* h  = (unsigned short*)(ws + WS_H_OFF);

    if (ws_size >= WS_NEEDED) {
        unsigned* slot = (unsigned*)(ws + WS_SLOT_OFF);
        int*      ovfc = (int*)     (ws + WS_OVFC_OFF);
        uint2*    ovf  = (uint2*)   (ws + WS_OVF_OFF);

        // zero slot rows (inline cnts) + overflow counter/array in one memset
        hipMemsetAsync(slot, 0, WS_ZERO_BYTES, stream);
        wprep_kernel<<<8, 256, 0, stream>>>(W, Wf);
        prep_kernel<<<SCAT_BLOCKS + GEMM_BLOCKS, 512, 0, stream>>>(
            x, Wf, bias, h, (const int4*)rows, (const int4*)cols,
            (const float4*)vals, slot, ovfc, ovf);
        spmm_kernel<<<(NV + 3) / 4, 256, 0, stream>>>(slot, ovfc, ovf, h, out);
    } else {
        wprep_kernel<<<8, 256, 0, stream>>>(W, Wf);
        gemm_only_kernel<<<GEMM_BLOCKS, 512, 0, stream>>>(x, Wf, bias, h);
        hipMemsetAsync(d_out, 0, (size_t)out_size * sizeof(float), stream);
        long long waves = (long long)NE * NB;
        int spmmBlocks = (int)((waves + 3) / 4);
        spmm_atomic_kernel<<<spmmBlocks, 256, 0, stream>>>(rows, cols, vals, h, out);
    }
}

// Round 12
// 110.474 us; speedup vs baseline: 1.1476x; 1.1476x over previous
//
#include <hip/hip_runtime.h>

// GraphConv: h = x @ W + b, then out[b,r] = sum_e vals[e]*h[b,cols[e]]
// B=2, V=50000, C=128, F=128, E=800000
// Round 12: ZERO-global-atomic CSR build via LDS counting sort.
//   K1: router (64 blocks stream edges once -> per-(p,k) staging, LDS
//       counters, single-writer XCD-local stores)  || MFMA gemm blocks.
//   K2: per-(p,k) LDS histogram -> C[k][r] (u16).
//   K3: per-row scan over 64 chunks -> bases (in-place) + deg[r].
//   K4: per-(p,k) placement: LDS rank counters -> pure stores to slot[r][48],
//       partition pinned to XCD (p = bid&15).
//   spmm: one wave/row, both batches, 16-wide MLP chunks (round 10 shape).

#define NB 2
#define NV 50000
#define NC 128
#define NF 128
#define NE 800000
#define NROW (NB * NV)       // 100000

#define NP 16                // row partitions
#define PR (NV / NP)         // 3125 rows per partition
#define NK 64                // edge chunks
#define CQ (NE / 4 / NK)     // 3125 quads per chunk
#define CAP_PK 1024          // staging entries per (p,k); Poisson(781)+8.7sigma
#define CAP 48               // slot entries per row; Poisson(16)+8sigma

#define GEMM_BLOCKS ((NROW + 127) / 128)     // 782

// ---- workspace layout (bytes) ----
#define WS_WF_OFF    0UL
#define WS_WF_BYTES  32768UL
#define WS_H_OFF     (WS_WF_OFF + WS_WF_BYTES)
#define WS_H_BYTES   ((size_t)NROW * NF * 2UL)                 // 25,600,000
#define WS_STG_OFF   (WS_H_OFF + WS_H_BYTES)
#define WS_STG_BYTES ((size_t)NP * NK * CAP_PK * 8UL)          // 8,388,608
#define WS_SC_OFF    (WS_STG_OFF + WS_STG_BYTES)
#define WS_SC_BYTES  ((size_t)NP * NK * 4UL)                   // 4,096
#define WS_C_OFF     (WS_SC_OFF + WS_SC_BYTES)
#define WS_C_BYTES   ((size_t)NK * NV * 2UL)                   // 6,400,000
#define WS_DEG_OFF   (WS_C_OFF + WS_C_BYTES)
#define WS_DEG_BYTES ((size_t)NV * 4UL)                        // 200,000
#define WS_SLOT_OFF  (WS_DEG_OFF + WS_DEG_BYTES)
#define WS_SLOT_BYTES ((size_t)NV * CAP * 4UL)                 // 9,600,000
#define WS_NEEDED    (WS_SLOT_OFF + WS_SLOT_BYTES)             // ~50.2 MB

typedef __attribute__((ext_vector_type(8))) short short8v;  // 8 bf16 bits
typedef __attribute__((ext_vector_type(4))) float f32x4;

// fp32 -> bf16 bits, round-to-nearest-even
__device__ __forceinline__ unsigned short f2b(float f) {
    unsigned int u = __float_as_uint(f);
    u += 0x7fffu + ((u >> 16) & 1u);
    return (unsigned short)(u >> 16);
}

// ---------------- Kernel 0: W -> frag-linear bf16 (once) ----------------
__global__ __launch_bounds__(256) void wprep_kernel(
    const float* __restrict__ W, unsigned short* __restrict__ Wf) {
    int s = blockIdx.x * 256 + threadIdx.x;
    if (s >= 2048) return;
    int lane = s & 63;
    int nt = (s >> 6) & 7;
    int ks = s >> 9;
    int n = nt * 16 + (lane & 15);
    int kb = ks * 32 + ((lane >> 4) & 3) * 8;
    short8v f;
#pragma unroll
    for (int j = 0; j < 8; ++j)
        f[j] = (short)f2b(W[(kb + j) * NF + n]);
    *(short8v*)(Wf + (size_t)s * 8) = f;
}

// ---------------- K1: router (blocks 0..NK-1) || gemm (rest) ----------------
__global__ __launch_bounds__(512) void k1_kernel(
    const float* __restrict__ x, const unsigned short* __restrict__ Wf,
    const float* __restrict__ bias, unsigned short* __restrict__ h,
    const int4* __restrict__ rows4, const int4* __restrict__ cols4,
    const float4* __restrict__ vals4, uint2* __restrict__ stg,
    int* __restrict__ SC) {
    int tid = threadIdx.x;

    if (blockIdx.x < NK) {
        __shared__ int lcnt[NP];
        int k = blockIdx.x;
        if (tid < NP) lcnt[tid] = 0;
        __syncthreads();
        int base = k * CQ;
        for (int i = tid; i < CQ; i += 512) {
            int t = base + i;
            int4 r4 = rows4[t];
            int4 c4 = cols4[t];
            float4 v4 = vals4[t];
            int rr[4] = {r4.x, r4.y, r4.z, r4.w};
            int cc[4] = {c4.x, c4.y, c4.z, c4.w};
            float vv[4] = {v4.x, v4.y, v4.z, v4.w};
#pragma unroll
            for (int q = 0; q < 4; ++q) {
                int p = rr[q] / PR;             // compile-time divisor
                int rl = rr[q] - p * PR;
                int pos = atomicAdd(&lcnt[p], 1);   // LDS atomic
                if (pos < CAP_PK)
                    stg[((size_t)p * NK + k) * CAP_PK + pos] =
                        make_uint2(((unsigned)rl << 16) | (unsigned)cc[q],
                                   __float_as_uint(vv[q]));
            }
        }
        __syncthreads();
        if (tid < NP) SC[tid * NK + k] = min(lcnt[tid], CAP_PK);
        return;
    }

    // ---------------- GEMM part (bf16 MFMA, frag-linear Wf from global) ----
    int gb = blockIdx.x - NK;
    int wid = tid >> 6;
    int lane = tid & 63;
    long long rowbase = (long long)gb * 128 + wid * 16;
    if (rowbase >= NROW) return;

    int arow = (int)rowbase + (lane & 15);
    int khi = lane >> 4;
    f32x4 acc[8];
#pragma unroll
    for (int n = 0; n < 8; ++n) acc[n] = (f32x4){0.f, 0.f, 0.f, 0.f};

#pragma unroll
    for (int ks = 0; ks < 4; ++ks) {
        const float* xp = x + (size_t)arow * NC + ks * 32 + khi * 8;
        float4 xlo = *(const float4*)xp;
        float4 xhi = *(const float4*)(xp + 4);
        short8v af;
        af[0] = (short)f2b(xlo.x); af[1] = (short)f2b(xlo.y);
        af[2] = (short)f2b(xlo.z); af[3] = (short)f2b(xlo.w);
        af[4] = (short)f2b(xhi.x); af[5] = (short)f2b(xhi.y);
        af[6] = (short)f2b(xhi.z); af[7] = (short)f2b(xhi.w);
#pragma unroll
        for (int nt = 0; nt < 8; ++nt) {
            short8v bf = *(const short8v*)(Wf + ((size_t)(ks * 8 + nt) * 64 + lane) * 8);
            acc[nt] = __builtin_amdgcn_mfma_f32_16x16x32_bf16(af, bf, acc[nt], 0, 0, 0);
        }
    }

    int rq = (lane >> 4) * 4;
#pragma unroll
    for (int nt = 0; nt < 8; ++nt) {
        int c = nt * 16 + (lane & 15);
        float bv = bias[c];
#pragma unroll
        for (int reg = 0; reg < 4; ++reg) {
            long long r = rowbase + rq + reg;
            int node = (r >= NV) ? (int)(r - NV) : (int)r;
            int bb = (r >= NV) ? 1 : 0;
            h[(size_t)node * 256 + bb * 128 + c] = f2b(acc[nt][reg] + bv);
        }
    }
}

// ---------------- K2: per-(p,k) LDS histogram -> C[k][r] (u16) -------------
__global__ __launch_bounds__(256) void k2_kernel(
    const uint2* __restrict__ stg, const int* __restrict__ SC,
    unsigned short* __restrict__ C) {
    __shared__ unsigned int hcnt[PR];
    int p = blockIdx.x & (NP - 1);
    int k = blockIdx.x >> 4;
    int tid = threadIdx.x;
    for (int j = tid; j < PR; j += 256) hcnt[j] = 0;
    __syncthreads();
    int n = SC[p * NK + k];
    const uint2* sp = stg + ((size_t)p * NK + k) * CAP_PK;
    for (int i = tid; i < n; i += 256) {
        unsigned rl = sp[i].x >> 16;
        atomicAdd(&hcnt[rl], 1u);
    }
    __syncthreads();
    int lo = p * PR;
    for (int j = tid; j < PR; j += 256)
        C[(size_t)k * NV + lo + j] = (unsigned short)hcnt[j];
}

// ---------------- K3: per-row scan over chunks -> bases + deg --------------
__global__ __launch_bounds__(256) void k3_kernel(
    unsigned short* __restrict__ C, int* __restrict__ deg) {
    int r = blockIdx.x * 256 + threadIdx.x;
    if (r >= NV) return;
    int run = 0;
#pragma unroll 8
    for (int k = 0; k < NK; ++k) {
        size_t idx = (size_t)k * NV + r;
        int t = C[idx];
        C[idx] = (unsigned short)run;
        run += t;
    }
    deg[r] = run;
}

// ---------------- K4: placement, pure stores (XCD-pinned partitions) -------
__global__ __launch_bounds__(256) void k4_kernel(
    const uint2* __restrict__ stg, const int* __restrict__ SC,
    const unsigned short* __restrict__ C, unsigned* __restrict__ slot) {
    __shared__ unsigned short base[PR];
    __shared__ unsigned int cnt2[PR];
    int p = blockIdx.x & (NP - 1);     // partition pinned to XCD bid%8
    int k = blockIdx.x >> 4;
    int tid = threadIdx.x;
    int lo = p * PR;
    for (int j = tid; j < PR; j += 256) {
        base[j] = C[(size_t)k * NV + lo + j];
        cnt2[j] = 0;
    }
    __syncthreads();
    int n = SC[p * NK + k];
    const uint2* sp = stg + ((size_t)p * NK + k) * CAP_PK;
    for (int i = tid; i < n; i += 256) {
        uint2 e = sp[i];
        unsigned rl = e.x >> 16;
        unsigned col = e.x & 0xffffu;
        unsigned rank = atomicAdd(&cnt2[rl], 1u);   // LDS atomic
        unsigned pos = (unsigned)base[rl] + rank;
        if (pos < CAP)
            slot[(size_t)(lo + rl) * CAP + pos] =
                (col << 16) | (unsigned)f2b(__uint_as_float(e.y));
    }
}

// ---------------- spmm: one wave/row, BOTH batches, 16-wide chunks ---------
__global__ __launch_bounds__(256) void spmm_kernel(
    const int* __restrict__ deg, const unsigned* __restrict__ slot,
    const unsigned short* __restrict__ h, float* __restrict__ out) {
    int r = (blockIdx.x * 256 + threadIdx.x) >> 6;
    int lane = threadIdx.x & 63;
    if (r >= NV) return;
    int n = min(deg[r], CAP);
    const unsigned* sp = slot + (size_t)r * CAP;
    const unsigned short* hl = h + lane * 2;
    float a0x = 0.f, a0y = 0.f, a1x = 0.f, a1y = 0.f;

    for (int i = 0; i < n; i += 16) {
        unsigned pk[16];
#pragma unroll
        for (int k = 0; k < 16; ++k) {
            int j = i + k;
            pk[k] = (j < n) ? sp[j] : 0u;   // col 0, val 0 (harmless)
        }
        unsigned q0[16], q1[16];
#pragma unroll
        for (int k = 0; k < 16; ++k) {
            size_t base = (size_t)(pk[k] >> 16) * 256;
            q0[k] = *(const unsigned int*)(hl + base);
            q1[k] = *(const unsigned int*)(hl + base + 128);
        }
#pragma unroll
        for (int k = 0; k < 16; ++k) {
            float v = __uint_as_float((pk[k] & 0xffffu) << 16);
            a0x = fmaf(v, __uint_as_float(q0[k] << 16), a0x);
            a0y = fmaf(v, __uint_as_float(q0[k] & 0xffff0000u), a0y);
            a1x = fmaf(v, __uint_as_float(q1[k] << 16), a1x);
            a1y = fmaf(v, __uint_as_float(q1[k] & 0xffff0000u), a1y);
        }
    }
    *(float2*)(out + (size_t)r * NF + lane * 2) = make_float2(a0x, a0y);
    *(float2*)(out + ((size_t)NV + r) * NF + lane * 2) = make_float2(a1x, a1y);
}

// ---------------- Fallback (ws too small): atomic spmm --------------------
__global__ __launch_bounds__(256) void spmm_atomic_kernel(
    const int* __restrict__ rows, const int* __restrict__ cols,
    const float* __restrict__ vals, const unsigned short* __restrict__ h,
    float* __restrict__ out) {
    long long wave = ((long long)blockIdx.x * blockDim.x + threadIdx.x) >> 6;
    int lane = threadIdx.x & 63;
    long long total = (long long)NE * NB;
    if (wave >= total) return;
    int b = (wave >= NE) ? 1 : 0;
    int e = (int)(wave - (long long)b * NE);
    int r = rows[e];
    int c = cols[e];
    float v = vals[e];
    unsigned int hv = *(const unsigned int*)(h + (size_t)c * 256 + b * 128 + lane * 2);
    float h0 = __uint_as_float(hv << 16);
    float h1 = __uint_as_float(hv & 0xffff0000u);
    float* op = out + ((size_t)b * NV + r) * NF + lane * 2;
    atomicAdd(op + 0, v * h0);
    atomicAdd(op + 1, v * h1);
}

// gemm-only for the fallback path
__global__ __launch_bounds__(512) void gemm_only_kernel(
    const float* __restrict__ x, const unsigned short* __restrict__ Wf,
    const float* __restrict__ bias, unsigned short* __restrict__ h) {
    int tid = threadIdx.x;
    int wid = tid >> 6;
    int lane = tid & 63;
    long long rowbase = (long long)blockIdx.x * 128 + wid * 16;
    if (rowbase >= NROW) return;
    int arow = (int)rowbase + (lane & 15);
    int khi = lane >> 4;
    f32x4 acc[8];
#pragma unroll
    for (int n = 0; n < 8; ++n) acc[n] = (f32x4){0.f, 0.f, 0.f, 0.f};
#pragma unroll
    for (int ks = 0; ks < 4; ++ks) {
        const float* xp = x + (size_t)arow * NC + ks * 32 + khi * 8;
        float4 xlo = *(const float4*)xp;
        float4 xhi = *(const float4*)(xp + 4);
        short8v af;
        af[0] = (short)f2b(xlo.x); af[1] = (short)f2b(xlo.y);
        af[2] = (short)f2b(xlo.z); af[3] = (short)f2b(xlo.w);
        af[4] = (short)f2b(xhi.x); af[5] = (short)f2b(xhi.y);
        af[6] = (short)f2b(xhi.z); af[7] = (short)f2b(xhi.w);
#pragma unroll
        for (int nt = 0; nt < 8; ++nt) {
            short8v bf = *(const short8v*)(Wf + ((size_t)(ks * 8 + nt) * 64 + lane) * 8);
            acc[nt] = __builtin_amdgcn_mfma_f32_16x16x32_bf16(af, bf, acc[nt], 0, 0, 0);
        }
    }
    int rq = (lane >> 4) * 4;
#pragma unroll
    for (int nt = 0; nt < 8; ++nt) {
        int c = nt * 16 + (lane & 15);
        float bv = bias[c];
#pragma unroll
        for (int reg = 0; reg < 4; ++reg) {
            long long r = rowbase + rq + reg;
            int node = (r >= NV) ? (int)(r - NV) : (int)r;
            int bb = (r >= NV) ? 1 : 0;
            h[(size_t)node * 256 + bb * 128 + c] = f2b(acc[nt][reg] + bv);
        }
    }
}

extern "C" void kernel_launch(void* const* d_in, const int* in_sizes, int n_in,
                              void* d_out, int out_size, void* d_ws, size_t ws_size,
                              hipStream_t stream) {
    const float* x    = (const float*)d_in[0];
    const int*   rows = (const int*)  d_in[1];
    const int*   cols = (const int*)  d_in[2];
    const float* vals = (const float*)d_in[3];
    const float* W    = (const float*)d_in[4];
    const float* bias = (const float*)d_in[5];
    float* out = (float*)d_out;
    char* ws = (char*)d_ws;

    unsigned short* Wf = (unsigned short*)(ws + WS_WF_OFF);
    unsigned short* h  = (unsigned short*)(ws + WS_H_OFF);

    wprep_kernel<<<8, 256, 0, stream>>>(W, Wf);

    if (ws_size >= WS_NEEDED) {
        uint2*          stg  = (uint2*)         (ws + WS_STG_OFF);
        int*            SC   = (int*)           (ws + WS_SC_OFF);
        unsigned short* C    = (unsigned short*)(ws + WS_C_OFF);
        int*            deg  = (int*)           (ws + WS_DEG_OFF);
        unsigned*       slot = (unsigned*)      (ws + WS_SLOT_OFF);

        k1_kernel<<<NK + GEMM_BLOCKS, 512, 0, stream>>>(
            x, Wf, bias, h, (const int4*)rows, (const int4*)cols,
            (const float4*)vals, stg, SC);
        k2_kernel<<<NP * NK, 256, 0, stream>>>(stg, SC, C);
        k3_kernel<<<(NV + 255) / 256, 256, 0, stream>>>(C, deg);
        k4_kernel<<<NP * NK, 256, 0, stream>>>(stg, SC, C, slot);
        spmm_kernel<<<(NV + 3) / 4, 256, 0, stream>>>(deg, slot, h, out);
    } else {
        gemm_only_kernel<<<GEMM_BLOCKS, 512, 0, stream>>>(x, Wf, bias, h);
        hipMemsetAsync(d_out, 0, (size_t)out_size * sizeof(float), stream);
        long long waves = (long long)NE * NB;
        int spmmBlocks = (int)((waves + 3) / 4);
        spmm_atomic_kernel<<<spmmBlocks, 256, 0, stream>>>(rows, cols, vals, h, out);
    }
}